// Round 1
// baseline (23.008 us; speedup 1.0000x reference)
//
#include <hip/hip_runtime.h>

#define NQ 5

__global__ __launch_bounds__(256) void amber_dyn_kernel(
    const float* __restrict__ state,  // [B,10]
    const float* __restrict__ u,      // [B,4]
    float* __restrict__ out,          // [B,10]
    int B)
{
    int idx = blockIdx.x * blockDim.x + threadIdx.x;
    if (idx >= B) return;

    // ---- load state row (40 B, 8-byte aligned -> float2 x5) ----
    const float2* st2 = reinterpret_cast<const float2*>(state + (size_t)idx * 10);
    float2 r0 = st2[0], r1 = st2[1], r2 = st2[2], r3 = st2[3], r4 = st2[4];
    float q[5]  = {r0.x, r0.y, r1.x, r1.y, r2.x};
    float qd[5] = {r2.y, r3.x, r3.y, r4.x, r4.y};

    // ---- load u row (16 B aligned) ----
    float4 uv = reinterpret_cast<const float4*>(u)[idx];

    // ---- trig ----
    float s[5], c[5];
    #pragma unroll
    for (int i = 0; i < 5; ++i) __sincosf(q[i], &s[i], &c[i]);

    float v2 = qd[0]*qd[0] + qd[1]*qd[1] + qd[2]*qd[2] + qd[3]*qd[3] + qd[4]*qd[4];
    float coef = 0.1f * v2 + 9.8f;

    // rhs = B@u - H ;  B@u = [0, u0, u1, u2, u3]
    float bu[5] = {0.f, uv.x, uv.y, uv.z, uv.w};
    float rhs[5];
    #pragma unroll
    for (int i = 0; i < 5; ++i)
        rhs[i] = bu[i] - (coef * s[i] + 0.05f * qd[i]);

    // D = 2I + 0.3*(c c^T + s s^T)   (cos(qi-qj) = ci*cj + si*sj)
    float D[5][5];
    #pragma unroll
    for (int i = 0; i < 5; ++i) {
        #pragma unroll
        for (int j = 0; j < 5; ++j) {
            float v = 0.3f * (c[i]*c[j] + s[i]*s[j]);
            D[i][j] = (i == j) ? (v + 2.0f) : v;
        }
    }

    // ---- solve D x = rhs : Gaussian elimination, no pivoting ----
    // (D strictly diagonally dominant: diag >= 2.3 - but actually 2.3 exactly
    //  on diag, off-diag sum <= 1.2, so elimination is stable)
    #pragma unroll
    for (int k = 0; k < 5; ++k) {
        float inv = 1.0f / D[k][k];
        #pragma unroll
        for (int r = k + 1; r < 5; ++r) {
            float m = D[r][k] * inv;
            #pragma unroll
            for (int cc = k + 1; cc < 5; ++cc)
                D[r][cc] -= m * D[k][cc];
            rhs[r] -= m * rhs[k];
        }
    }
    float x[5];
    #pragma unroll
    for (int k = 4; k >= 0; --k) {
        float acc = rhs[k];
        #pragma unroll
        for (int cc = k + 1; cc < 5; ++cc) acc -= D[k][cc] * x[cc];
        x[k] = acc / D[k][k];
    }

    // ---- store out row: [qd[0..4], x[0..4]] (40 B, 8-byte aligned) ----
    float2* o2 = reinterpret_cast<float2*>(out + (size_t)idx * 10);
    o2[0] = make_float2(qd[0], qd[1]);
    o2[1] = make_float2(qd[2], qd[3]);
    o2[2] = make_float2(qd[4], x[0]);
    o2[3] = make_float2(x[1],  x[2]);
    o2[4] = make_float2(x[3],  x[4]);
}

extern "C" void kernel_launch(void* const* d_in, const int* in_sizes, int n_in,
                              void* d_out, int out_size, void* d_ws, size_t ws_size,
                              hipStream_t stream) {
    // inputs (setup_inputs order): t [1], state [B*10], u [B*4]
    const float* state = (const float*)d_in[1];
    const float* u     = (const float*)d_in[2];
    float* out = (float*)d_out;
    int B = in_sizes[1] / 10;

    int block = 256;
    int grid = (B + block - 1) / block;
    amber_dyn_kernel<<<grid, block, 0, stream>>>(state, u, out, B);
}